// Round 1
// 69.123 us; speedup vs baseline: 1.0007x; 1.0007x over previous
//
#include <hip/hip_runtime.h>

// Problem constants (from reference setup_inputs):
//   bs=4, v=8192, n=20, SUPPORT_NUM=4, KERNEL_NUM=32
#define BS 4
#define NV 8192
#define NN 20
#define SN 4
#define KN 32

#define KPT 2               // k-columns per thread (float2 path)
#define TPG (KN / KPT)      // 16 threads per (b,v) group
#define GP  16              // (b,v) groups per batch
#define BLOCK (GP * TPG)    // 256 threads
#define NB 2                // batches per block (software pipeline)
#define SLOTS (GP * NN)     // 320 gather slots per batch
#define LDP (NN + 1)        // padded LDS stride in float4 (21): groups land on
                            // disjoint bank quads (84 dwords mod 32 = 20)

// R4: latency-hiding restructure.
//  - kernel was ~27us vs ~6us pipe floors (dur_us includes a fixed ~42us
//    harness ws-poison fill) -> latency-bound, not throughput-bound.
//  - KPT=2 halves LDS-pipe work (20 ds_read_b128 per 2 columns, not per 1).
//  - relu-after-max: m init 0, pairwise v_max3 folds -> 560 VALU/thread.
//  - NB=2 pipeline: all idx loads issued first (two-hop chain broken);
//    batch-B gather loads stay in flight across batch-A compute.
//  - grid = 1024 blocks = 4096 waves = exactly 4 waves/SIMD resident
//    (whole grid co-resident, single round, no tail).
__global__ __launch_bounds__(BLOCK, 4) void op3d_kernel(
    const int*   __restrict__ nbr,     // (BS, NV, NN)
    const float* __restrict__ verts,   // (BS, NV, 3)
    const float* __restrict__ wgt,     // (1,1,SN,KN) -> (SN,KN)
    const float* __restrict__ disp,    // (3, SN*KN)
    float*       __restrict__ out)     // (BS, NV, KN)
{
    __shared__ float4 sdx[NB][GP * LDP];   // 2 x 5376 B = 10752 B

    const int tx     = threadIdx.x;
    const int batchA = blockIdx.x * NB;
    const int batchB = batchA + 1;

    // ---- neighbor-index loads for BOTH batches, issued first ----
    const int  i0   = tx;             // slots 0..255
    const int  i1   = tx + BLOCK;     // slots 256..319 (tx < 64)
    const bool has1 = (i1 < SLOTS);
    const int idxA0 = nbr[(size_t)batchA * SLOTS + i0];
    const int idxB0 = nbr[(size_t)batchB * SLOTS + i0];
    int idxA1 = 0, idxB1 = 0;
    if (has1) {
        idxA1 = nbr[(size_t)batchA * SLOTS + i1];
        idxB1 = nbr[(size_t)batchB * SLOTS + i1];
    }

    // ---- per-thread column constants (L1-resident; overlaps idx latency) ----
    const int kk = (tx & (TPG - 1)) * KPT;
    const int g  = tx / TPG;
    float2 D0[SN], D1[SN], D2[SN], w[SN];
#pragma unroll
    for (int s = 0; s < SN; ++s) {
        const int col = s * KN + kk;
        D0[s] = *(const float2*)(disp + 0 * SN * KN + col);
        D1[s] = *(const float2*)(disp + 1 * SN * KN + col);
        D2[s] = *(const float2*)(disp + 2 * SN * KN + col);
        w[s]  = *(const float2*)(wgt  + col);
    }

    const int gi0 = i0 / NN, j0 = i0 - gi0 * NN;   // magic-mul div by 20
    const int gi1 = i1 / NN, j1 = i1 - gi1 * NN;

    // ---- gather batch A -> LDS buf 0 ----
    {
        const int bv = batchA * GP + gi0;
        const float* np = verts + ((size_t)(bv & ~(NV - 1)) + idxA0) * 3;
        const float* vp = verts + (size_t)bv * 3;
        const float4 d = make_float4(np[0] - vp[0], np[1] - vp[1], np[2] - vp[2], 0.f);
        float4 d1 = make_float4(0.f, 0.f, 0.f, 0.f);
        if (has1) {
            const int bv1 = batchA * GP + gi1;
            const float* np1 = verts + ((size_t)(bv1 & ~(NV - 1)) + idxA1) * 3;
            const float* vp1 = verts + (size_t)bv1 * 3;
            d1 = make_float4(np1[0] - vp1[0], np1[1] - vp1[1], np1[2] - vp1[2], 0.f);
        }
        sdx[0][gi0 * LDP + j0] = d;
        if (has1) sdx[0][gi1 * LDP + j1] = d1;
    }
    __syncthreads();

    // ---- issue batch-B gather loads NOW; they fly across compute A ----
    float nx0, ny0, nz0, vx0, vy0, vz0;
    {
        const int bv = batchB * GP + gi0;
        const float* np = verts + ((size_t)(bv & ~(NV - 1)) + idxB0) * 3;
        const float* vp = verts + (size_t)bv * 3;
        nx0 = np[0]; ny0 = np[1]; nz0 = np[2];
        vx0 = vp[0]; vy0 = vp[1]; vz0 = vp[2];
    }
    float nx1 = 0.f, ny1 = 0.f, nz1 = 0.f, vx1 = 0.f, vy1 = 0.f, vz1 = 0.f;
    if (has1) {
        const int bv = batchB * GP + gi1;
        const float* np = verts + ((size_t)(bv & ~(NV - 1)) + idxB1) * 3;
        const float* vp = verts + (size_t)bv * 3;
        nx1 = np[0]; ny1 = np[1]; nz1 = np[2];
        vx1 = vp[0]; vy1 = vp[1]; vz1 = vp[2];
    }

    // ---- compute phase: 10 j-pairs, 2 columns, relu folded into final max ----
    auto compute_store = [&](int buf, int batch) {
        const float4* sg = &sdx[buf][g * LDP];
        float2 m[SN];
#pragma unroll
        for (int s = 0; s < SN; ++s) m[s] = make_float2(0.f, 0.f);
#pragma unroll
        for (int jp = 0; jp < NN / 2; ++jp) {          // imm-offset ds_read_b128 x2
            const float4 da = sg[2 * jp];
            const float4 db = sg[2 * jp + 1];
#pragma unroll
            for (int s = 0; s < SN; ++s) {
                const float ta0 = fmaf(da.x, D0[s].x, fmaf(da.y, D1[s].x, da.z * D2[s].x));
                const float tb0 = fmaf(db.x, D0[s].x, fmaf(db.y, D1[s].x, db.z * D2[s].x));
                const float ta1 = fmaf(da.x, D0[s].y, fmaf(da.y, D1[s].y, da.z * D2[s].y));
                const float tb1 = fmaf(db.x, D0[s].y, fmaf(db.y, D1[s].y, db.z * D2[s].y));
                m[s].x = fmaxf(m[s].x, fmaxf(ta0, tb0));   // v_max3_f32
                m[s].y = fmaxf(m[s].y, fmaxf(ta1, tb1));   // v_max3_f32
            }
        }
        float accx = 0.f, accy = 0.f;
#pragma unroll
        for (int s = 0; s < SN; ++s) {
            accx = fmaf(m[s].x, w[s].x, accx);
            accy = fmaf(m[s].y, w[s].y, accy);
        }
        const int bv = batch * GP + g;
        *(float2*)(out + (size_t)bv * KN + kk) = make_float2(accx, accy);  // coalesced
    };

    // ---- compute A (hides batch-B gather latency) ----
    compute_store(0, batchA);

    // ---- stage batch B -> LDS buf 1 (vmcnt wait lands here) ----
    sdx[1][gi0 * LDP + j0] = make_float4(nx0 - vx0, ny0 - vy0, nz0 - vz0, 0.f);
    if (has1) sdx[1][gi1 * LDP + j1] = make_float4(nx1 - vx1, ny1 - vy1, nz1 - vz1, 0.f);
    __syncthreads();

    // ---- compute B ----
    compute_store(1, batchB);
}

extern "C" void kernel_launch(void* const* d_in, const int* in_sizes, int n_in,
                              void* d_out, int out_size, void* d_ws, size_t ws_size,
                              hipStream_t stream) {
    const int*   nbr   = (const int*)d_in[0];    // neighbor_index (4,8192,20)
    const float* verts = (const float*)d_in[1];  // vertices (4,8192,3)
    const float* wgt   = (const float*)d_in[2];  // weights (1,1,4,32)
    const float* disp  = (const float*)d_in[3];  // displacement (3,128)
    float* out = (float*)d_out;                  // (4,8192,32)

    const int grid = (BS * NV) / (GP * NB);      // 1024 blocks, whole grid resident
    op3d_kernel<<<grid, BLOCK, 0, stream>>>(nbr, verts, wgt, disp, out);
}